// Round 12
// baseline (320.980 us; speedup 1.0000x reference)
//
#include <hip/hip_runtime.h>

#define NEG_INF -1e10f
#define B_   8
#define LQ_  2048
#define LK_  2048
#define D_   1024

typedef unsigned int uint;
typedef unsigned short u16;
typedef _Float16 f16;
typedef _Float16 f16x8_t __attribute__((ext_vector_type(8)));
typedef float f32x4_t __attribute__((ext_vector_type(4)));

// ---------- helpers ----------
__device__ __forceinline__ u16 f2h_bits(float f) {
    f16 h = (f16)f;
    return __builtin_bit_cast(u16, h);
}
__device__ __forceinline__ float h2f(u16 b) {
    return (float)__builtin_bit_cast(f16, b);
}
__device__ __forceinline__ void gload_lds16(const void* g, void* l) {
    __builtin_amdgcn_global_load_lds(
        (const __attribute__((address_space(1))) uint*)g,
        (__attribute__((address_space(3))) uint*)l, 16, 0, 0);
}

// ---------- fp32 -> (hi,lo) fp16 split (Q path) ----------
__global__ __launch_bounds__(256) void convert_q_hilo(
    const float4* __restrict__ src, ushort4* __restrict__ hi,
    ushort4* __restrict__ lo, int n4)
{
    int idx = blockIdx.x * 256 + threadIdx.x;
    const int stride = gridDim.x * 256;
    for (; idx < n4; idx += stride) {
        float4 x = src[idx];
        ushort4 h, l;
        h.x = f2h_bits(x.x); l.x = f2h_bits(x.x - h2f(h.x));
        h.y = f2h_bits(x.y); l.y = f2h_bits(x.y - h2f(h.y));
        h.z = f2h_bits(x.z); l.z = f2h_bits(x.z - h2f(h.z));
        h.w = f2h_bits(x.w); l.w = f2h_bits(x.w - h2f(h.w));
        hi[idx] = h; lo[idx] = l;
    }
}

// ---------- fp32 -> fp16 (K path) ----------
__global__ __launch_bounds__(256) void convert_f16(
    const float4* __restrict__ src, ushort4* __restrict__ dst, int n4)
{
    int idx = blockIdx.x * 256 + threadIdx.x;
    const int stride = gridDim.x * 256;
    for (; idx < n4; idx += stride) {
        float4 x = src[idx];
        ushort4 h;
        h.x = f2h_bits(x.x);
        h.y = f2h_bits(x.y);
        h.z = f2h_bits(x.z);
        h.w = f2h_bits(x.w);
        dst[idx] = h;
    }
}

// ---------- V [z][2048][1024] fp32 -> VT [z][1024][2048] fp16 ----------
__global__ __launch_bounds__(256) void transpose_convert(
    const float* __restrict__ V, u16* __restrict__ VT)
{
    __shared__ float tile[64][65];
    const int t  = threadIdx.x;
    const int d0 = blockIdx.x * 64;
    const int k0 = blockIdx.y * 64;
    const float* Vb = V + (size_t)blockIdx.z * (LK_ * D_);
    u16* VTb = VT + (size_t)blockIdx.z * (D_ * LK_);
#pragma unroll
    for (int i = 0; i < 4; ++i) {
        int f = i * 256 + t;
        int r = f >> 4, c4 = f & 15;
        float4 v = *(const float4*)&Vb[(size_t)(k0 + r) * D_ + d0 + c4 * 4];
        tile[r][c4 * 4 + 0] = v.x;
        tile[r][c4 * 4 + 1] = v.y;
        tile[r][c4 * 4 + 2] = v.z;
        tile[r][c4 * 4 + 3] = v.w;
    }
    __syncthreads();
#pragma unroll
    for (int i = 0; i < 4; ++i) {
        int f = i * 256 + t;
        int d = f >> 4, c4 = f & 15;
        ushort4 o;
        o.x = f2h_bits(tile[c4 * 4 + 0][d]);
        o.y = f2h_bits(tile[c4 * 4 + 1][d]);
        o.z = f2h_bits(tile[c4 * 4 + 2][d]);
        o.w = f2h_bits(tile[c4 * 4 + 3][d]);
        *(ushort4*)&VTb[(size_t)(d0 + d) * LK_ + k0 + c4 * 4] = o;
    }
}

// ===================================================================
// 8-phase counted-vmcnt GEMM, virtual K = 2048.  R12: LDS reads are
// plain C++ vector loads (compiler emits fine-grained lgkmcnt so the
// first MFMA starts as soon as ITS operands land; remaining reads
// overlap the MFMA cluster).  Raw s_barrier (no implicit vmcnt drain)
// + asm counted vmcnt with "memory" clobber preserve the T4 pipeline.
// Ledger (unchanged from R7/R9/R11):
//   buf[t&3] staged during tile t-3; vmcnt(8) at end of tile t-1
//   leaves only tiles t+1,t+2 outstanding -> tile t's stages complete;
//   barrier makes them visible.  Reads of buf[t&3] are consumed by
//   tile t's MFMAs (compiler lgkmcnt precedes them), sealed by the
//   trailing barrier before tile t+4's staging can land.
// ===================================================================
#define BM_  256
#define BK_  32
#define NT_  64

template<int NBF>
__global__ __launch_bounds__(512, 2) void gemm8p(
    const u16* __restrict__ A0g, const u16* __restrict__ A1g,
    const u16* __restrict__ Bg, float* __restrict__ Cg,
    int lda, int ldb, int ldc, int bkmask,
    size_t szA, size_t szB, size_t szC)
{
    constexpr int BN     = 64 * NBF;
    constexpr int ABYTES = BM_ * BK_ * 2;          // 16384
    constexpr int BBYTES = BN * BK_ * 2;           // 16384 / 8192
    constexpr int BUFSZ  = ABYTES + BBYTES;        // 32768 / 24576
    __shared__ char lds[4 * BUFSZ];

    const int tid  = threadIdx.x;
    const int lane = tid & 63;
    const int w    = tid >> 6;           // 0..7
    const int wm   = w >> 2;             // 0..1
    const int wn   = w & 3;              // 0..3

    // ---- T1 XCD 2x4 rectangle remap (8x8 tile grid) ----
    const int d  = blockIdx.x;           // 0..63
    const int g  = d & 7;                // xcd (heuristic: bid % 8)
    const int k_ = d >> 3;               // 0..7 within rectangle
    const int by = (g >> 1) * 2 + (k_ & 1);        // m-row 0..7
    const int bx = (g & 1) * 4 + (k_ >> 1);        // n-col 0..7
    const int m0 = by * BM_;
    const int n0 = bx * BN;
    const size_t z = blockIdx.y;

    const u16* A0 = A0g + z * szA;
    const u16* A1 = A1g + z * szA;
    const u16* B  = Bg  + z * szB;
    float* C = Cg + z * szC;

    const int  lr   = lane & 15;
    // T2 swizzle (R7-verified, conflicts=0): chunk' = chunk ^ ((row>>1)&3)
    const uint csel = (uint)((((lane >> 4) ^ ((lane >> 1) & 3)) * 16));
    const int  cstg = (((lane & 3) ^ ((lane >> 3) & 3)) * 8);  // stage src chunk
    const int  rstg = lane >> 2;                               // stage row in 16-row grp

    const uint awoff = (uint)(wm * 8192 + lr * 64) + csel;
    const uint bwoff = (uint)(wn * (NBF * 1024) + lr * 64) + csel;

    f32x4_t acc[8][NBF];
#pragma unroll
    for (int m = 0; m < 8; ++m)
#pragma unroll
        for (int n = 0; n < NBF; ++n)
            acc[m][n] = (f32x4_t){0.f, 0.f, 0.f, 0.f};

    // ---- staging (per wave; LDS dest linear, global src swizzled) ----
    auto stA = [&](int t) {
        const u16* Ab = (t < NT_ / 2) ? A0 : A1;
        const int kc = (t & (NT_ / 2 - 1)) * BK_ + cstg;
        char* dst = lds + (t & 3) * BUFSZ + w * 2048;
        gload_lds16(&Ab[(size_t)(m0 + w * 32 + rstg) * lda + kc], dst);
        gload_lds16(&Ab[(size_t)(m0 + w * 32 + 16 + rstg) * lda + kc], dst + 1024);
    };
    auto stB = [&](int t) {
        const int kc = ((t * BK_) & bkmask) + cstg;
        char* dst = lds + (t & 3) * BUFSZ + ABYTES;
        if constexpr (NBF == 4) {
            gload_lds16(&B[(size_t)(n0 + w * 32 + rstg) * ldb + kc], dst + w * 2048);
            gload_lds16(&B[(size_t)(n0 + w * 32 + 16 + rstg) * ldb + kc], dst + w * 2048 + 1024);
        } else {
            gload_lds16(&B[(size_t)(n0 + w * 16 + rstg) * ldb + kc], dst + w * 1024);
        }
    };

    // ---- prologue: stage tiles 0,1,2; wait tile 0 (counted) ----
    stA(0); stB(0); stA(1); stB(1); stA(2); stB(2);
    if constexpr (NBF == 4) asm volatile("s_waitcnt vmcnt(8)" ::: "memory");
    else                    asm volatile("s_waitcnt vmcnt(6)" ::: "memory");
    __builtin_amdgcn_s_barrier();

#define LDF(p) (*(const f16x8_t*)(p))

#define PHASE_A(T, DOSTAGE)                                                   \
    {                                                                         \
        const char* pA = lds + ((T) & 3) * BUFSZ + awoff;                     \
        const char* pB = lds + ((T) & 3) * BUFSZ + ABYTES + bwoff;            \
        f16x8_t a[4], b[NBF];                                                 \
        a[0] = LDF(pA);        a[1] = LDF(pA + 1024);                         \
        a[2] = LDF(pA + 2048); a[3] = LDF(pA + 3072);                         \
        b[0] = LDF(pB);                                                       \
        if constexpr (NBF >= 2) b[1] = LDF(pB + 1024);                        \
        if constexpr (NBF == 4) { b[2] = LDF(pB + 2048); b[3] = LDF(pB + 3072); } \
        if (DOSTAGE) stA((T) + 3);                                            \
        __builtin_amdgcn_s_barrier();                                         \
        __builtin_amdgcn_s_setprio(1);                                        \
        _Pragma("unroll")                                                     \
        for (int mf = 0; mf < 4; ++mf)                                        \
            _Pragma("unroll")                                                 \
            for (int nf = 0; nf < NBF; ++nf)                                  \
                acc[mf][nf] = __builtin_amdgcn_mfma_f32_16x16x32_f16(         \
                    a[mf], b[nf], acc[mf][nf], 0, 0, 0);                      \
        __builtin_amdgcn_s_setprio(0);                                        \
        bsave[0] = b[0];                                                      \
        if constexpr (NBF >= 2) bsave[1] = b[1];                              \
        if constexpr (NBF == 4) { bsave[2] = b[2]; bsave[3] = b[3]; }         \
        __builtin_amdgcn_s_barrier();                                         \
    }

#define PHASE_B(T, DOSTAGE, VMASM)                                            \
    {                                                                         \
        const char* pA = lds + ((T) & 3) * BUFSZ + awoff;                     \
        f16x8_t a[4];                                                         \
        a[0] = LDF(pA + 4096); a[1] = LDF(pA + 5120);                         \
        a[2] = LDF(pA + 6144); a[3] = LDF(pA + 7168);                         \
        if (DOSTAGE) stB((T) + 3);                                            \
        __builtin_amdgcn_s_barrier();                                         \
        __builtin_amdgcn_s_setprio(1);                                        \
        _Pragma("unroll")                                                     \
        for (int mf = 0; mf < 4; ++mf)                                        \
            _Pragma("unroll")                                                 \
            for (int nf = 0; nf < NBF; ++nf)                                  \
                acc[4 + mf][nf] = __builtin_amdgcn_mfma_f32_16x16x32_f16(     \
                    a[mf], bsave[nf], acc[4 + mf][nf], 0, 0, 0);              \
        __builtin_amdgcn_s_setprio(0);                                        \
        VMASM;                                                                \
        __builtin_amdgcn_s_barrier();                                         \
    }

#define VMW do { if constexpr (NBF == 4) asm volatile("s_waitcnt vmcnt(8)" ::: "memory"); \
                 else asm volatile("s_waitcnt vmcnt(6)" ::: "memory"); } while (0)
#define VMH do { if constexpr (NBF == 4) asm volatile("s_waitcnt vmcnt(4)" ::: "memory"); \
                 else asm volatile("s_waitcnt vmcnt(3)" ::: "memory"); } while (0)
#define VM0 asm volatile("s_waitcnt vmcnt(0)" ::: "memory")
#define VMN do {} while (0)

    f16x8_t bsave[NBF];

    // ---- main loop: steps 0..NT_-4 stage tile t+3, counted vmcnt ----
    for (int t = 0; t < NT_ - 3; ++t) {
        PHASE_A(t, true);
        PHASE_B(t, true, VMW);
    }
    // ---- peeled tail: no stages; shrink vmcnt ----
    PHASE_A(NT_ - 3, false); PHASE_B(NT_ - 3, false, VMH);
    PHASE_A(NT_ - 2, false); PHASE_B(NT_ - 2, false, VM0);
    PHASE_A(NT_ - 1, false); PHASE_B(NT_ - 1, false, VMN);
#undef PHASE_A
#undef PHASE_B
#undef LDF

    // ---- epilogue: C write (fp32) ----
    const int cg = lane >> 4;
#pragma unroll
    for (int mf = 0; mf < 8; ++mf)
#pragma unroll
        for (int nf = 0; nf < NBF; ++nf) {
            const int row = m0 + wm * 128 + mf * 16 + cg * 4;
            const int col = n0 + wn * (NBF * 16) + nf * 16 + lr;
#pragma unroll
            for (int r = 0; r < 4; ++r)
                C[(size_t)(row + r) * ldc + col] = acc[mf][nf][r];
        }
}

// ---------- masked row softmax, z-batched: S fp32 -> P fp16 IN PLACE ----------
__global__ __launch_bounds__(256) void softmax_mask(
    float* __restrict__ S, const int* __restrict__ mask0)
{
    const int lane = threadIdx.x & 63;
    const int wave = threadIdx.x >> 6;
    const int row  = blockIdx.x * 4 + wave;
    const size_t zb = blockIdx.y;
    float* Sr = S + (zb * LQ_ + row) * (size_t)LK_;
    const int* mb = mask0 + zb * LK_;

    float4 s[8];
    float m = -INFINITY;
#pragma unroll
    for (int i = 0; i < 8; ++i) {
        int k = i * 256 + lane * 4;
        float4 v = *(const float4*)&Sr[k];
        int4 mk  = *(const int4*)&mb[k];
        v.x = mk.x ? v.x : NEG_INF;
        v.y = mk.y ? v.y : NEG_INF;
        v.z = mk.z ? v.z : NEG_INF;
        v.w = mk.w ? v.w : NEG_INF;
        s[i] = v;
        m = fmaxf(m, fmaxf(fmaxf(v.x, v.y), fmaxf(v.z, v.w)));
    }
#pragma unroll
    for (int off = 32; off > 0; off >>= 1)
        m = fmaxf(m, __shfl_xor(m, off, 64));
    float sum = 0.f;
#pragma unroll
    for (int i = 0; i < 8; ++i) {
        s[i].x = __expf(s[i].x - m); sum += s[i].x;
        s[i].y = __expf(s[i].y - m); sum += s[i].y;
        s[i].z = __expf(s[i].z - m); sum += s[i].z;
        s[i].w = __expf(s[i].w - m); sum += s[i].w;
    }
#pragma unroll
    for (int off = 32; off > 0; off >>= 1)
        sum += __shfl_xor(sum, off, 64);
    const float inv = 1.f / sum;
    u16* Pr = (u16*)Sr;
#pragma unroll
    for (int i = 0; i < 8; ++i) {
        int k = i * 256 + lane * 4;
        ushort4 o;
        o.x = f2h_bits(s[i].x * inv);
        o.y = f2h_bits(s[i].y * inv);
        o.z = f2h_bits(s[i].z * inv);
        o.w = f2h_bits(s[i].w * inv);
        *(ushort4*)&Pr[k] = o;
    }
}

// ---------- fallback (verified R1 fp32 kernel) ----------
__global__ __launch_bounds__(256, 2) void attn_fp32_flash(
    const float* __restrict__ hidden, const float* __restrict__ keys,
    const float* __restrict__ values, const int* __restrict__ mask,
    float* __restrict__ out)
{
    const int lane = threadIdx.x & 63;
    const int wave = threadIdx.x >> 6;
    const int blk  = blockIdx.x;
    const int b    = blk >> 7;
    const int q0   = (blk & 127) * 16 + wave * 4;
    float4 q[4][4]; float4 o[4][4]; float m[4], s[4];
    const float4* hp = (const float4*)(hidden + ((size_t)b * LQ_ + q0) * D_);
#pragma unroll
    for (int r = 0; r < 4; ++r) {
#pragma unroll
        for (int j = 0; j < 4; ++j) {
            q[r][j] = hp[r * 256 + j * 64 + lane];
            o[r][j] = make_float4(0.f, 0.f, 0.f, 0.f);
        }
        m[r] = -INFINITY; s[r] = 0.f;
    }
    const float4* kp = (const float4*)(keys   + (size_t)b * LK_ * D_);
    const float4* vp = (const float4*)(values + (size_t)b * LK_ * D_);
    const int*    mp = mask + b * LK_;
    for (int k = 0; k < LK_; ++k) {
        float4 kv[4];
#pragma unroll
        for (int j = 0; j < 4; ++j) kv[j] = kp[k * 256 + j * 64 + lane];
        float sc[4];
#pragma unroll
        for (int r = 0; r < 4; ++r) {
            float p = 0.f;
#pragma unroll
            for (int j = 0; j < 4; ++j)
                p += q[r][j].x * kv[j].x + q[r][j].y * kv[j].y +
                     q[r][j].z * kv[j].z + q[r][j].w * kv[j].w;
            sc[r] = p;
        }
#pragma unroll
        for (int r = 0; r < 4; ++r)
#pragma unroll
            for (int off = 32; off > 0; off >>= 1)
                sc[r] += __shfl_xor(sc[r], off, 64);
        const int mk = mp[k];
        float4 vv[4];
#pragma unroll
        for (int j = 0; j < 4; ++j) vv[j] = vp[k * 256 + j * 64 + lane];
#pragma unroll
        for (int r = 0; r < 4; ++r) {
            float score = mk ? sc[r] : NEG_INF;
            if (score > m[r]) {
                float scale = __expf(m[r] - score);
                m[r] = score; s[r] *= scale;
#pragma unroll
                for (int j = 0; j < 4; ++j) {
                    o[r][j].x *= scale; o[r][j].y *= scale;
                    o[r][j].z *= scale; o[r][j].w *= scale;
                }
            }
            float e = __expf(score - m[r]);
            s[r] += e;
#pragma unroll
            for (int j = 0; j < 4; ++j) {
                o[r][j].x += e * vv[j].x; o[r][j].y += e * vv[j].y;
                o[r][j].z += e * vv[j].z; o[r][j].w += e * vv[j].w;
            }
        }
    }
    float4* op = (float4*)(out + ((size_t)b * LQ_ + q0) * D_);
#pragma unroll
    for (int r = 0; r < 4; ++r) {
        float inv = 1.f / s[r];
#pragma unroll
        for (int j = 0; j < 4; ++j) {
            float4 t = o[r][j];
            t.x *= inv; t.y *= inv; t.z *= inv; t.w *= inv;
            op[r * 256 + j * 64 + lane] = t;
        }
    }
}

extern "C" void kernel_launch(void* const* d_in, const int* in_sizes, int n_in,
                              void* d_out, int out_size, void* d_ws, size_t ws_size,
                              hipStream_t stream) {
    const float* hidden = (const float*)d_in[0];
    const float* keys   = (const float*)d_in[1];
    const float* values = (const float*)d_in[2];
    const int*   mask   = (const int*)d_in[3];
    float* out = (float*)d_out;
    char* ws = (char*)d_ws;

    const size_t TEN = (size_t)LK_ * D_;          // 2M elems per batch tensor
    const size_t MB  = 1024ull * 1024;

    // per-batch footprint: Kh 4 + VT 4 + Qh 4 + Ql 4 + S 16 (P in place) = 32 MiB
    int BG = 0;
    for (int g = 8; g >= 1; g >>= 1)
        if ((size_t)g * 32 * MB <= ws_size) { BG = g; break; }

    if (BG == 0) {
        attn_fp32_flash<<<1024, 256, 0, stream>>>(hidden, keys, values, mask, out);
        return;
    }

    const size_t SZ_BF = (size_t)BG * TEN * 2;            // BG*4 MiB per u16 tensor
    u16*   Kh = (u16*)(ws);
    u16*   VT = (u16*)(ws + SZ_BF);
    u16*   Qh = (u16*)(ws + 2 * SZ_BF);
    u16*   Ql = (u16*)(ws + 3 * SZ_BF);
    float* S  = (float*)(ws + 4 * SZ_BF);                 // BG*16 MiB

    const int n4 = BG * (int)(TEN / 4);

    for (int bg0 = 0; bg0 < B_; bg0 += BG) {
        const size_t off = (size_t)bg0 * TEN;
        convert_f16<<<2048, 256, 0, stream>>>(
            (const float4*)(keys + off), (ushort4*)Kh, n4);
        transpose_convert<<<dim3(16, 32, BG), 256, 0, stream>>>(
            values + off, VT);
        convert_q_hilo<<<2048, 256, 0, stream>>>(
            (const float4*)(hidden + off), (ushort4*)Qh, (ushort4*)Ql, n4);

        // S = [Qh|Ql] * [Kh|Kh]^T  — virtual K=2048, 8-phase, XCD-remapped
        gemm8p<4><<<dim3(64, BG), 512, 0, stream>>>(
            Qh, Ql, Kh, S, D_, D_, LK_, 1023,
            TEN, TEN, (size_t)LQ_ * LK_);

        // softmax, P written fp16 in place over the first half of each S row
        softmax_mask<<<dim3(LQ_ / 4, BG), 256, 0, stream>>>(
            S, mask + bg0 * LK_);

        // out = P * VT^T — P rows at stride 4096 u16 (8 KiB) inside S;
        // virtual K=2048 via A1 = P + 1024, bkmask 2047
        gemm8p<2><<<dim3(64, BG), 512, 0, stream>>>(
            (const u16*)S, (const u16*)S + 1024, VT, out + off,
            2 * LK_, LK_, D_, 2047,
            (size_t)LQ_ * 2 * LK_, TEN, (size_t)LQ_ * D_);
    }
}

// Round 13
// 257.800 us; speedup vs baseline: 1.2451x; 1.2451x over previous
//
#include <hip/hip_runtime.h>

#define NEG_INF -1e10f
#define B_   8
#define LQ_  2048
#define LK_  2048
#define D_   1024

typedef unsigned int uint;
typedef unsigned short u16;
typedef _Float16 f16;
typedef _Float16 f16x8_t __attribute__((ext_vector_type(8)));
typedef float f32x4_t __attribute__((ext_vector_type(4)));

// ---------- helpers ----------
__device__ __forceinline__ u16 f2h_bits(float f) {
    f16 h = (f16)f;
    return __builtin_bit_cast(u16, h);
}
__device__ __forceinline__ void gload_lds16(const void* g, void* l) {
    __builtin_amdgcn_global_load_lds(
        (const __attribute__((address_space(1))) uint*)g,
        (__attribute__((address_space(3))) uint*)l, 16, 0, 0);
}

// ---------- fp32 -> fp16 ----------
__global__ __launch_bounds__(256) void convert_f16(
    const float4* __restrict__ src, ushort4* __restrict__ dst, int n4)
{
    int idx = blockIdx.x * 256 + threadIdx.x;
    const int stride = gridDim.x * 256;
    for (; idx < n4; idx += stride) {
        float4 x = src[idx];
        ushort4 h;
        h.x = f2h_bits(x.x);
        h.y = f2h_bits(x.y);
        h.z = f2h_bits(x.z);
        h.w = f2h_bits(x.w);
        dst[idx] = h;
    }
}

// ---------- V [z][2048][1024] fp32 -> VT [z][1024][2048] fp16 ----------
__global__ __launch_bounds__(256) void transpose_convert(
    const float* __restrict__ V, u16* __restrict__ VT)
{
    __shared__ float tile[64][65];
    const int t  = threadIdx.x;
    const int d0 = blockIdx.x * 64;
    const int k0 = blockIdx.y * 64;
    const float* Vb = V + (size_t)blockIdx.z * (LK_ * D_);
    u16* VTb = VT + (size_t)blockIdx.z * (D_ * LK_);
#pragma unroll
    for (int i = 0; i < 4; ++i) {
        int f = i * 256 + t;
        int r = f >> 4, c4 = f & 15;
        float4 v = *(const float4*)&Vb[(size_t)(k0 + r) * D_ + d0 + c4 * 4];
        tile[r][c4 * 4 + 0] = v.x;
        tile[r][c4 * 4 + 1] = v.y;
        tile[r][c4 * 4 + 2] = v.z;
        tile[r][c4 * 4 + 3] = v.w;
    }
    __syncthreads();
#pragma unroll
    for (int i = 0; i < 4; ++i) {
        int f = i * 256 + t;
        int d = f >> 4, c4 = f & 15;
        ushort4 o;
        o.x = f2h_bits(tile[c4 * 4 + 0][d]);
        o.y = f2h_bits(tile[c4 * 4 + 1][d]);
        o.z = f2h_bits(tile[c4 * 4 + 2][d]);
        o.w = f2h_bits(tile[c4 * 4 + 3][d]);
        *(ushort4*)&VTb[(size_t)(d0 + d) * LK_ + k0 + c4 * 4] = o;
    }
}

// ===================================================================
// 8-phase counted-vmcnt GEMM (R11/R12-verified schedule).
//  SPLIT=true : virtual K = NTILES*32 with A-pointer switch at half
//               (PV: P rows in S at stride lda, A1 = A0 + 1024).
//  SPLIT=false: straight K = NTILES*32 from A0 (QK pure fp16).
//  T1 XCD 2x4 remap; T2 swizzle (conflicts=0); launch_bounds(512,2).
// ===================================================================
#define BM_  256
#define BK_  32

template<int NBF, int NTILES, bool SPLIT>
__global__ __launch_bounds__(512, 2) void gemm8p(
    const u16* __restrict__ A0g, const u16* __restrict__ A1g,
    const u16* __restrict__ Bg, float* __restrict__ Cg,
    int lda, int ldb, int ldc, int bkmask,
    size_t szA, size_t szB, size_t szC)
{
    constexpr int BN     = 64 * NBF;
    constexpr int ABYTES = BM_ * BK_ * 2;          // 16384
    constexpr int BBYTES = BN * BK_ * 2;           // 16384 / 8192
    constexpr int BUFSZ  = ABYTES + BBYTES;        // 32768 / 24576
    __shared__ char lds[4 * BUFSZ];

    const int tid  = threadIdx.x;
    const int lane = tid & 63;
    const int w    = tid >> 6;           // 0..7
    const int wm   = w >> 2;             // 0..1
    const int wn   = w & 3;              // 0..3

    // ---- T1 XCD 2x4 rectangle remap (8x8 tile grid) ----
    const int d  = blockIdx.x;           // 0..63
    const int g  = d & 7;                // xcd (heuristic: bid % 8)
    const int k_ = d >> 3;               // 0..7 within rectangle
    const int by = (g >> 1) * 2 + (k_ & 1);        // m-row 0..7
    const int bx = (g & 1) * 4 + (k_ >> 1);        // n-col 0..7
    const int m0 = by * BM_;
    const int n0 = bx * BN;
    const size_t z = blockIdx.y;

    const u16* A0 = A0g + z * szA;
    const u16* A1 = A1g + z * szA;
    const u16* B  = Bg  + z * szB;
    float* C = Cg + z * szC;

    const int  lr   = lane & 15;
    // T2 swizzle (R7-verified, conflicts=0): chunk' = chunk ^ ((row>>1)&3)
    const uint csel = (uint)((((lane >> 4) ^ ((lane >> 1) & 3)) * 16));
    const int  cstg = (((lane & 3) ^ ((lane >> 3) & 3)) * 8);  // stage src chunk
    const int  rstg = lane >> 2;                               // stage row in 16-row grp

    const uint awoff = (uint)(wm * 8192 + lr * 64) + csel;
    const uint bwoff = (uint)(wn * (NBF * 1024) + lr * 64) + csel;

    f32x4_t acc[8][NBF];
#pragma unroll
    for (int m = 0; m < 8; ++m)
#pragma unroll
        for (int n = 0; n < NBF; ++n)
            acc[m][n] = (f32x4_t){0.f, 0.f, 0.f, 0.f};

    // ---- staging (per wave; LDS dest linear, global src swizzled) ----
    auto stA = [&](int t) {
        const u16* Ab;
        int kc;
        if constexpr (SPLIT) {
            Ab = (t < NTILES / 2) ? A0 : A1;
            kc = (t & (NTILES / 2 - 1)) * BK_ + cstg;
        } else {
            Ab = A0;
            kc = t * BK_ + cstg;
        }
        char* dst = lds + (t & 3) * BUFSZ + w * 2048;
        gload_lds16(&Ab[(size_t)(m0 + w * 32 + rstg) * lda + kc], dst);
        gload_lds16(&Ab[(size_t)(m0 + w * 32 + 16 + rstg) * lda + kc], dst + 1024);
    };
    auto stB = [&](int t) {
        const int kc = ((t * BK_) & bkmask) + cstg;
        char* dst = lds + (t & 3) * BUFSZ + ABYTES;
        if constexpr (NBF == 4) {
            gload_lds16(&B[(size_t)(n0 + w * 32 + rstg) * ldb + kc], dst + w * 2048);
            gload_lds16(&B[(size_t)(n0 + w * 32 + 16 + rstg) * ldb + kc], dst + w * 2048 + 1024);
        } else {
            gload_lds16(&B[(size_t)(n0 + w * 16 + rstg) * ldb + kc], dst + w * 1024);
        }
    };

    // ---- prologue: stage tiles 0,1,2; wait tile 0 (counted) ----
    stA(0); stB(0); stA(1); stB(1); stA(2); stB(2);
    if constexpr (NBF == 4) asm volatile("s_waitcnt vmcnt(8)" ::: "memory");
    else                    asm volatile("s_waitcnt vmcnt(6)" ::: "memory");
    __builtin_amdgcn_s_barrier();

#define LDF(p) (*(const f16x8_t*)(p))

#define PHASE_A(T, DOSTAGE)                                                   \
    {                                                                         \
        const char* pA = lds + ((T) & 3) * BUFSZ + awoff;                     \
        const char* pB = lds + ((T) & 3) * BUFSZ + ABYTES + bwoff;            \
        f16x8_t a[4], b[NBF];                                                 \
        a[0] = LDF(pA);        a[1] = LDF(pA + 1024);                         \
        a[2] = LDF(pA + 2048); a[3] = LDF(pA + 3072);                         \
        b[0] = LDF(pB);                                                       \
        if constexpr (NBF >= 2) b[1] = LDF(pB + 1024);                        \
        if constexpr (NBF == 4) { b[2] = LDF(pB + 2048); b[3] = LDF(pB + 3072); } \
        if (DOSTAGE) stA((T) + 3);                                            \
        __builtin_amdgcn_s_barrier();                                         \
        __builtin_amdgcn_s_setprio(1);                                        \
        _Pragma("unroll")                                                     \
        for (int mf = 0; mf < 4; ++mf)                                        \
            _Pragma("unroll")                                                 \
            for (int nf = 0; nf < NBF; ++nf)                                  \
                acc[mf][nf] = __builtin_amdgcn_mfma_f32_16x16x32_f16(         \
                    a[mf], b[nf], acc[mf][nf], 0, 0, 0);                      \
        __builtin_amdgcn_s_setprio(0);                                        \
        bsave[0] = b[0];                                                      \
        if constexpr (NBF >= 2) bsave[1] = b[1];                              \
        if constexpr (NBF == 4) { bsave[2] = b[2]; bsave[3] = b[3]; }         \
        __builtin_amdgcn_s_barrier();                                         \
    }

#define PHASE_B(T, DOSTAGE, VMASM)                                            \
    {                                                                         \
        const char* pA = lds + ((T) & 3) * BUFSZ + awoff;                     \
        f16x8_t a[4];                                                         \
        a[0] = LDF(pA + 4096); a[1] = LDF(pA + 5120);                         \
        a[2] = LDF(pA + 6144); a[3] = LDF(pA + 7168);                         \
        if (DOSTAGE) stB((T) + 3);                                            \
        __builtin_amdgcn_s_barrier();                                         \
        __builtin_amdgcn_s_setprio(1);                                        \
        _Pragma("unroll")                                                     \
        for (int mf = 0; mf < 4; ++mf)                                        \
            _Pragma("unroll")                                                 \
            for (int nf = 0; nf < NBF; ++nf)                                  \
                acc[4 + mf][nf] = __builtin_amdgcn_mfma_f32_16x16x32_f16(     \
                    a[mf], bsave[nf], acc[4 + mf][nf], 0, 0, 0);              \
        __builtin_amdgcn_s_setprio(0);                                        \
        VMASM;                                                                \
        __builtin_amdgcn_s_barrier();                                         \
    }

#define VMW do { if constexpr (NBF == 4) asm volatile("s_waitcnt vmcnt(8)" ::: "memory"); \
                 else asm volatile("s_waitcnt vmcnt(6)" ::: "memory"); } while (0)
#define VMH do { if constexpr (NBF == 4) asm volatile("s_waitcnt vmcnt(4)" ::: "memory"); \
                 else asm volatile("s_waitcnt vmcnt(3)" ::: "memory"); } while (0)
#define VM0 asm volatile("s_waitcnt vmcnt(0)" ::: "memory")
#define VMN do {} while (0)

    f16x8_t bsave[NBF];

    // ---- main loop: steps 0..NTILES-4 stage tile t+3, counted vmcnt ----
    for (int t = 0; t < NTILES - 3; ++t) {
        PHASE_A(t, true);
        PHASE_B(t, true, VMW);
    }
    // ---- peeled tail: no stages; shrink vmcnt ----
    PHASE_A(NTILES - 3, false); PHASE_B(NTILES - 3, false, VMH);
    PHASE_A(NTILES - 2, false); PHASE_B(NTILES - 2, false, VM0);
    PHASE_A(NTILES - 1, false); PHASE_B(NTILES - 1, false, VMN);
#undef PHASE_A
#undef PHASE_B
#undef LDF

    // ---- epilogue: C write (fp32) ----
    const int cg = lane >> 4;
#pragma unroll
    for (int mf = 0; mf < 8; ++mf)
#pragma unroll
        for (int nf = 0; nf < NBF; ++nf) {
            const int row = m0 + wm * 128 + mf * 16 + cg * 4;
            const int col = n0 + wn * (NBF * 16) + nf * 16 + lr;
#pragma unroll
            for (int r = 0; r < 4; ++r)
                C[(size_t)(row + r) * ldc + col] = acc[mf][nf][r];
        }
}

// ---------- masked row softmax, z-batched: S fp32 -> P fp16 IN PLACE ----------
__global__ __launch_bounds__(256) void softmax_mask(
    float* __restrict__ S, const int* __restrict__ mask0)
{
    const int lane = threadIdx.x & 63;
    const int wave = threadIdx.x >> 6;
    const int row  = blockIdx.x * 4 + wave;
    const size_t zb = blockIdx.y;
    float* Sr = S + (zb * LQ_ + row) * (size_t)LK_;
    const int* mb = mask0 + zb * LK_;

    float4 s[8];
    float m = -INFINITY;
#pragma unroll
    for (int i = 0; i < 8; ++i) {
        int k = i * 256 + lane * 4;
        float4 v = *(const float4*)&Sr[k];
        int4 mk  = *(const int4*)&mb[k];
        v.x = mk.x ? v.x : NEG_INF;
        v.y = mk.y ? v.y : NEG_INF;
        v.z = mk.z ? v.z : NEG_INF;
        v.w = mk.w ? v.w : NEG_INF;
        s[i] = v;
        m = fmaxf(m, fmaxf(fmaxf(v.x, v.y), fmaxf(v.z, v.w)));
    }
#pragma unroll
    for (int off = 32; off > 0; off >>= 1)
        m = fmaxf(m, __shfl_xor(m, off, 64));
    float sum = 0.f;
#pragma unroll
    for (int i = 0; i < 8; ++i) {
        s[i].x = __expf(s[i].x - m); sum += s[i].x;
        s[i].y = __expf(s[i].y - m); sum += s[i].y;
        s[i].z = __expf(s[i].z - m); sum += s[i].z;
        s[i].w = __expf(s[i].w - m); sum += s[i].w;
    }
#pragma unroll
    for (int off = 32; off > 0; off >>= 1)
        sum += __shfl_xor(sum, off, 64);
    const float inv = 1.f / sum;
    u16* Pr = (u16*)Sr;
#pragma unroll
    for (int i = 0; i < 8; ++i) {
        int k = i * 256 + lane * 4;
        ushort4 o;
        o.x = f2h_bits(s[i].x * inv);
        o.y = f2h_bits(s[i].y * inv);
        o.z = f2h_bits(s[i].z * inv);
        o.w = f2h_bits(s[i].w * inv);
        *(ushort4*)&Pr[k] = o;
    }
}

// ---------- fallback (verified R1 fp32 kernel) ----------
__global__ __launch_bounds__(256, 2) void attn_fp32_flash(
    const float* __restrict__ hidden, const float* __restrict__ keys,
    const float* __restrict__ values, const int* __restrict__ mask,
    float* __restrict__ out)
{
    const int lane = threadIdx.x & 63;
    const int wave = threadIdx.x >> 6;
    const int blk  = blockIdx.x;
    const int b    = blk >> 7;
    const int q0   = (blk & 127) * 16 + wave * 4;
    float4 q[4][4]; float4 o[4][4]; float m[4], s[4];
    const float4* hp = (const float4*)(hidden + ((size_t)b * LQ_ + q0) * D_);
#pragma unroll
    for (int r = 0; r < 4; ++r) {
#pragma unroll
        for (int j = 0; j < 4; ++j) {
            q[r][j] = hp[r * 256 + j * 64 + lane];
            o[r][j] = make_float4(0.f, 0.f, 0.f, 0.f);
        }
        m[r] = -INFINITY; s[r] = 0.f;
    }
    const float4* kp = (const float4*)(keys   + (size_t)b * LK_ * D_);
    const float4* vp = (const float4*)(values + (size_t)b * LK_ * D_);
    const int*    mp = mask + b * LK_;
    for (int k = 0; k < LK_; ++k) {
        float4 kv[4];
#pragma unroll
        for (int j = 0; j < 4; ++j) kv[j] = kp[k * 256 + j * 64 + lane];
        float sc[4];
#pragma unroll
        for (int r = 0; r < 4; ++r) {
            float p = 0.f;
#pragma unroll
            for (int j = 0; j < 4; ++j)
                p += q[r][j].x * kv[j].x + q[r][j].y * kv[j].y +
                     q[r][j].z * kv[j].z + q[r][j].w * kv[j].w;
            sc[r] = p;
        }
#pragma unroll
        for (int r = 0; r < 4; ++r)
#pragma unroll
            for (int off = 32; off > 0; off >>= 1)
                sc[r] += __shfl_xor(sc[r], off, 64);
        const int mk = mp[k];
        float4 vv[4];
#pragma unroll
        for (int j = 0; j < 4; ++j) vv[j] = vp[k * 256 + j * 64 + lane];
#pragma unroll
        for (int r = 0; r < 4; ++r) {
            float score = mk ? sc[r] : NEG_INF;
            if (score > m[r]) {
                float scale = __expf(m[r] - score);
                m[r] = score; s[r] *= scale;
#pragma unroll
                for (int j = 0; j < 4; ++j) {
                    o[r][j].x *= scale; o[r][j].y *= scale;
                    o[r][j].z *= scale; o[r][j].w *= scale;
                }
            }
            float e = __expf(score - m[r]);
            s[r] += e;
#pragma unroll
            for (int j = 0; j < 4; ++j) {
                o[r][j].x += e * vv[j].x; o[r][j].y += e * vv[j].y;
                o[r][j].z += e * vv[j].z; o[r][j].w += e * vv[j].w;
            }
        }
    }
    float4* op = (float4*)(out + ((size_t)b * LQ_ + q0) * D_);
#pragma unroll
    for (int r = 0; r < 4; ++r) {
        float inv = 1.f / s[r];
#pragma unroll
        for (int j = 0; j < 4; ++j) {
            float4 t = o[r][j];
            t.x *= inv; t.y *= inv; t.z *= inv; t.w *= inv;
            op[r * 256 + j * 64 + lane] = t;
        }
    }
}

extern "C" void kernel_launch(void* const* d_in, const int* in_sizes, int n_in,
                              void* d_out, int out_size, void* d_ws, size_t ws_size,
                              hipStream_t stream) {
    const float* hidden = (const float*)d_in[0];
    const float* keys   = (const float*)d_in[1];
    const float* values = (const float*)d_in[2];
    const int*   mask   = (const int*)d_in[3];
    float* out = (float*)d_out;
    char* ws = (char*)d_ws;

    const size_t TEN = (size_t)LK_ * D_;          // 2M elems per batch tensor
    const size_t MB  = 1024ull * 1024;

    // per-batch footprint: Kh 4 + VT 4 + Qh 4 + S 16 (P in place) = 28 MiB
    int BG = 0;
    for (int g = 8; g >= 1; g >>= 1)
        if ((size_t)g * 28 * MB <= ws_size) { BG = g; break; }

    if (BG == 0) {
        attn_fp32_flash<<<1024, 256, 0, stream>>>(hidden, keys, values, mask, out);
        return;
    }

    const size_t SZ_BF = (size_t)BG * TEN * 2;            // BG*4 MiB per u16 tensor
    u16*   Kh = (u16*)(ws);
    u16*   VT = (u16*)(ws + SZ_BF);
    u16*   Qh = (u16*)(ws + 2 * SZ_BF);
    float* S  = (float*)(ws + 3 * SZ_BF);                 // BG*16 MiB

    const int n4 = BG * (int)(TEN / 4);

    for (int bg0 = 0; bg0 < B_; bg0 += BG) {
        const size_t off = (size_t)bg0 * TEN;
        convert_f16<<<2048, 256, 0, stream>>>(
            (const float4*)(keys + off), (ushort4*)Kh, n4);
        transpose_convert<<<dim3(16, 32, BG), 256, 0, stream>>>(
            values + off, VT);
        convert_f16<<<2048, 256, 0, stream>>>(
            (const float4*)(hidden + off), (ushort4*)Qh, n4);

        // S = Qh * Kh^T — pure fp16, true K=1024 (32 tiles)
        gemm8p<4, 32, false><<<dim3(64, BG), 512, 0, stream>>>(
            Qh, Qh, Kh, S, D_, D_, LK_, 1023,
            TEN, TEN, (size_t)LQ_ * LK_);

        // softmax, P written fp16 in place over the first half of each S row
        softmax_mask<<<dim3(LQ_ / 4, BG), 256, 0, stream>>>(
            S, mask + bg0 * LK_);

        // out = P * VT^T — P rows at stride 4096 u16 inside S;
        // virtual K=2048 via A1 = P + 1024, bkmask 2047
        gemm8p<2, 64, true><<<dim3(64, BG), 512, 0, stream>>>(
            (const u16*)S, (const u16*)S + 1024, VT, out + off,
            2 * LK_, LK_, D_, 2047,
            (size_t)LQ_ * 2 * LK_, TEN, (size_t)LQ_ * D_);
    }
}

// Round 14
// 238.862 us; speedup vs baseline: 1.3438x; 1.0793x over previous
//
#include <hip/hip_runtime.h>

#define NEG_INF -1e10f
#define B_   8
#define LQ_  2048
#define LK_  2048
#define D_   1024

typedef unsigned int uint;
typedef unsigned short u16;
typedef _Float16 f16;
typedef _Float16 f16x8_t __attribute__((ext_vector_type(8)));
typedef float f32x4_t __attribute__((ext_vector_type(4)));

// ---------- helpers ----------
__device__ __forceinline__ u16 f2h_bits(float f) {
    f16 h = (f16)f;
    return __builtin_bit_cast(u16, h);
}
__device__ __forceinline__ void gload_lds16(const void* g, void* l) {
    __builtin_amdgcn_global_load_lds(
        (const __attribute__((address_space(1))) uint*)g,
        (__attribute__((address_space(3))) uint*)l, 16, 0, 0);
}

// ---------- fused fp32 -> fp16 for two tensors (K and Q) ----------
__global__ __launch_bounds__(256) void convert_f16_2(
    const float4* __restrict__ s1, ushort4* __restrict__ d1,
    const float4* __restrict__ s2, ushort4* __restrict__ d2, int n4)
{
    int idx = blockIdx.x * 256 + threadIdx.x;
    const int stride = gridDim.x * 256;
    for (; idx < 2 * n4; idx += stride) {
        const bool second = idx >= n4;
        const int i = second ? idx - n4 : idx;
        float4 x = second ? s2[i] : s1[i];
        ushort4 h;
        h.x = f2h_bits(x.x);
        h.y = f2h_bits(x.y);
        h.z = f2h_bits(x.z);
        h.w = f2h_bits(x.w);
        if (second) d2[i] = h; else d1[i] = h;
    }
}

// ---------- V [z][2048][1024] fp32 -> VT [z][1024][2048] fp16 ----------
__global__ __launch_bounds__(256) void transpose_convert(
    const float* __restrict__ V, u16* __restrict__ VT)
{
    __shared__ float tile[64][65];
    const int t  = threadIdx.x;
    const int d0 = blockIdx.x * 64;
    const int k0 = blockIdx.y * 64;
    const float* Vb = V + (size_t)blockIdx.z * (LK_ * D_);
    u16* VTb = VT + (size_t)blockIdx.z * (D_ * LK_);
#pragma unroll
    for (int i = 0; i < 4; ++i) {
        int f = i * 256 + t;
        int r = f >> 4, c4 = f & 15;
        float4 v = *(const float4*)&Vb[(size_t)(k0 + r) * D_ + d0 + c4 * 4];
        tile[r][c4 * 4 + 0] = v.x;
        tile[r][c4 * 4 + 1] = v.y;
        tile[r][c4 * 4 + 2] = v.z;
        tile[r][c4 * 4 + 3] = v.w;
    }
    __syncthreads();
#pragma unroll
    for (int i = 0; i < 4; ++i) {
        int f = i * 256 + t;
        int d = f >> 4, c4 = f & 15;
        ushort4 o;
        o.x = f2h_bits(tile[c4 * 4 + 0][d]);
        o.y = f2h_bits(tile[c4 * 4 + 1][d]);
        o.z = f2h_bits(tile[c4 * 4 + 2][d]);
        o.w = f2h_bits(tile[c4 * 4 + 3][d]);
        *(ushort4*)&VTb[(size_t)(d0 + d) * LK_ + k0 + c4 * 4] = o;
    }
}

// ===================================================================
// 8-phase counted-vmcnt GEMM (R11-R13-verified schedule), 256x256 tile.
//  SPLIT=false: QK — straight K = NTILES*32 from A0; 8x8 tile grid,
//               XCD owns a 2m x 4n rectangle.
//  SPLIT=true : PV — virtual K with A-pointer switch at half (P rows
//               in S at stride lda); 8m x 4n tile grid, XCD owns 2x2.
//  T2 swizzle (conflicts=0); launch_bounds(512,2) — register ledger
//  needs ~160+/wave (acc[8][4]=128 + frags + addr), so 2 waves/EU.
// ===================================================================
#define BM_  256
#define BK_  32

template<int NBF, int NTILES, bool SPLIT>
__global__ __launch_bounds__(512, 2) void gemm8p(
    const u16* __restrict__ A0g, const u16* __restrict__ A1g,
    const u16* __restrict__ Bg, float* __restrict__ Cg,
    int lda, int ldb, int ldc, int bkmask,
    size_t szA, size_t szB, size_t szC)
{
    constexpr int BN     = 64 * NBF;
    constexpr int ABYTES = BM_ * BK_ * 2;          // 16384
    constexpr int BBYTES = BN * BK_ * 2;           // 16384
    constexpr int BUFSZ  = ABYTES + BBYTES;        // 32768
    __shared__ char lds[4 * BUFSZ];

    const int tid  = threadIdx.x;
    const int lane = tid & 63;
    const int w    = tid >> 6;           // 0..7
    const int wm   = w >> 2;             // 0..1
    const int wn   = w & 3;              // 0..3

    // ---- T1 XCD rectangle remap ----
    const int d  = blockIdx.x;
    const int g  = d & 7;                // xcd (heuristic: bid % 8)
    const int k_ = d >> 3;
    int by, bx;
    if constexpr (!SPLIT) {              // QK: 8x8 grid, 2m x 4n rect
        by = (g >> 1) * 2 + (k_ & 1);
        bx = (g & 1) * 4 + (k_ >> 1);
    } else {                             // PV: 8m x 4n grid, 2m x 2n rect
        by = (g >> 1) * 2 + (k_ & 1);
        bx = (g & 1) * 2 + (k_ >> 1);
    }
    const int m0 = by * BM_;
    const int n0 = bx * BN;
    const size_t z = blockIdx.y;

    const u16* A0 = A0g + z * szA;
    const u16* A1 = A1g + z * szA;
    const u16* B  = Bg  + z * szB;
    float* C = Cg + z * szC;

    const int  lr   = lane & 15;
    // T2 swizzle (R7-verified, conflicts=0): chunk' = chunk ^ ((row>>1)&3)
    const uint csel = (uint)((((lane >> 4) ^ ((lane >> 1) & 3)) * 16));
    const int  cstg = (((lane & 3) ^ ((lane >> 3) & 3)) * 8);  // stage src chunk
    const int  rstg = lane >> 2;                               // stage row in 16-row grp

    const uint awoff = (uint)(wm * 8192 + lr * 64) + csel;
    const uint bwoff = (uint)(wn * (NBF * 1024) + lr * 64) + csel;

    f32x4_t acc[8][NBF];
#pragma unroll
    for (int m = 0; m < 8; ++m)
#pragma unroll
        for (int n = 0; n < NBF; ++n)
            acc[m][n] = (f32x4_t){0.f, 0.f, 0.f, 0.f};

    // ---- staging (per wave; LDS dest linear, global src swizzled) ----
    auto stA = [&](int t) {
        const u16* Ab;
        int kc;
        if constexpr (SPLIT) {
            Ab = (t < NTILES / 2) ? A0 : A1;
            kc = (t & (NTILES / 2 - 1)) * BK_ + cstg;
        } else {
            Ab = A0;
            kc = t * BK_ + cstg;
        }
        char* dst = lds + (t & 3) * BUFSZ + w * 2048;
        gload_lds16(&Ab[(size_t)(m0 + w * 32 + rstg) * lda + kc], dst);
        gload_lds16(&Ab[(size_t)(m0 + w * 32 + 16 + rstg) * lda + kc], dst + 1024);
    };
    auto stB = [&](int t) {
        const int kc = ((t * BK_) & bkmask) + cstg;
        char* dst = lds + (t & 3) * BUFSZ + ABYTES;
        gload_lds16(&B[(size_t)(n0 + w * 32 + rstg) * ldb + kc], dst + w * 2048);
        gload_lds16(&B[(size_t)(n0 + w * 32 + 16 + rstg) * ldb + kc], dst + w * 2048 + 1024);
    };

    // ---- prologue: stage tiles 0,1,2; wait tile 0 (counted) ----
    stA(0); stB(0); stA(1); stB(1); stA(2); stB(2);
    asm volatile("s_waitcnt vmcnt(8)" ::: "memory");
    __builtin_amdgcn_s_barrier();

#define LDF(p) (*(const f16x8_t*)(p))

#define PHASE_A(T, DOSTAGE)                                                   \
    {                                                                         \
        const char* pA = lds + ((T) & 3) * BUFSZ + awoff;                     \
        const char* pB = lds + ((T) & 3) * BUFSZ + ABYTES + bwoff;            \
        f16x8_t a[4], b[NBF];                                                 \
        a[0] = LDF(pA);        a[1] = LDF(pA + 1024);                         \
        a[2] = LDF(pA + 2048); a[3] = LDF(pA + 3072);                         \
        b[0] = LDF(pB);        b[1] = LDF(pB + 1024);                         \
        b[2] = LDF(pB + 2048); b[3] = LDF(pB + 3072);                         \
        if (DOSTAGE) stA((T) + 3);                                            \
        __builtin_amdgcn_s_barrier();                                         \
        __builtin_amdgcn_s_setprio(1);                                        \
        _Pragma("unroll")                                                     \
        for (int mf = 0; mf < 4; ++mf)                                        \
            _Pragma("unroll")                                                 \
            for (int nf = 0; nf < NBF; ++nf)                                  \
                acc[mf][nf] = __builtin_amdgcn_mfma_f32_16x16x32_f16(         \
                    a[mf], b[nf], acc[mf][nf], 0, 0, 0);                      \
        __builtin_amdgcn_s_setprio(0);                                        \
        bsave[0] = b[0]; bsave[1] = b[1]; bsave[2] = b[2]; bsave[3] = b[3];   \
        __builtin_amdgcn_s_barrier();                                         \
    }

#define PHASE_B(T, DOSTAGE, VMASM)                                            \
    {                                                                         \
        const char* pA = lds + ((T) & 3) * BUFSZ + awoff;                     \
        f16x8_t a[4];                                                         \
        a[0] = LDF(pA + 4096); a[1] = LDF(pA + 5120);                         \
        a[2] = LDF(pA + 6144); a[3] = LDF(pA + 7168);                         \
        if (DOSTAGE) stB((T) + 3);                                            \
        __builtin_amdgcn_s_barrier();                                         \
        __builtin_amdgcn_s_setprio(1);                                        \
        _Pragma("unroll")                                                     \
        for (int mf = 0; mf < 4; ++mf)                                        \
            _Pragma("unroll")                                                 \
            for (int nf = 0; nf < NBF; ++nf)                                  \
                acc[4 + mf][nf] = __builtin_amdgcn_mfma_f32_16x16x32_f16(     \
                    a[mf], bsave[nf], acc[4 + mf][nf], 0, 0, 0);              \
        __builtin_amdgcn_s_setprio(0);                                        \
        VMASM;                                                                \
        __builtin_amdgcn_s_barrier();                                         \
    }

#define VMW asm volatile("s_waitcnt vmcnt(8)" ::: "memory")
#define VMH asm volatile("s_waitcnt vmcnt(4)" ::: "memory")
#define VM0 asm volatile("s_waitcnt vmcnt(0)" ::: "memory")
#define VMN do {} while (0)

    f16x8_t bsave[NBF];

    // ---- main loop: steps 0..NTILES-4 stage tile t+3, counted vmcnt ----
    for (int t = 0; t < NTILES - 3; ++t) {
        PHASE_A(t, true);
        PHASE_B(t, true, VMW);
    }
    // ---- peeled tail: no stages; shrink vmcnt ----
    PHASE_A(NTILES - 3, false); PHASE_B(NTILES - 3, false, VMH);
    PHASE_A(NTILES - 2, false); PHASE_B(NTILES - 2, false, VM0);
    PHASE_A(NTILES - 1, false); PHASE_B(NTILES - 1, false, VMN);
#undef PHASE_A
#undef PHASE_B
#undef LDF

    // ---- epilogue: C write (fp32) ----
    const int cg = lane >> 4;
#pragma unroll
    for (int mf = 0; mf < 8; ++mf)
#pragma unroll
        for (int nf = 0; nf < NBF; ++nf) {
            const int row = m0 + wm * 128 + mf * 16 + cg * 4;
            const int col = n0 + wn * (NBF * 16) + nf * 16 + lr;
#pragma unroll
            for (int r = 0; r < 4; ++r)
                C[(size_t)(row + r) * ldc + col] = acc[mf][nf][r];
        }
}

// ---------- masked row softmax, z-batched: S fp32 -> P fp16 IN PLACE ----------
__global__ __launch_bounds__(256) void softmax_mask(
    float* __restrict__ S, const int* __restrict__ mask0)
{
    const int lane = threadIdx.x & 63;
    const int wave = threadIdx.x >> 6;
    const int row  = blockIdx.x * 4 + wave;
    const size_t zb = blockIdx.y;
    float* Sr = S + (zb * LQ_ + row) * (size_t)LK_;
    const int* mb = mask0 + zb * LK_;

    float4 s[8];
    float m = -INFINITY;
#pragma unroll
    for (int i = 0; i < 8; ++i) {
        int k = i * 256 + lane * 4;
        float4 v = *(const float4*)&Sr[k];
        int4 mk  = *(const int4*)&mb[k];
        v.x = mk.x ? v.x : NEG_INF;
        v.y = mk.y ? v.y : NEG_INF;
        v.z = mk.z ? v.z : NEG_INF;
        v.w = mk.w ? v.w : NEG_INF;
        s[i] = v;
        m = fmaxf(m, fmaxf(fmaxf(v.x, v.y), fmaxf(v.z, v.w)));
    }
#pragma unroll
    for (int off = 32; off > 0; off >>= 1)
        m = fmaxf(m, __shfl_xor(m, off, 64));
    float sum = 0.f;
#pragma unroll
    for (int i = 0; i < 8; ++i) {
        s[i].x = __expf(s[i].x - m); sum += s[i].x;
        s[i].y = __expf(s[i].y - m); sum += s[i].y;
        s[i].z = __expf(s[i].z - m); sum += s[i].z;
        s[i].w = __expf(s[i].w - m); sum += s[i].w;
    }
#pragma unroll
    for (int off = 32; off > 0; off >>= 1)
        sum += __shfl_xor(sum, off, 64);
    const float inv = 1.f / sum;
    u16* Pr = (u16*)Sr;
#pragma unroll
    for (int i = 0; i < 8; ++i) {
        int k = i * 256 + lane * 4;
        ushort4 o;
        o.x = f2h_bits(s[i].x * inv);
        o.y = f2h_bits(s[i].y * inv);
        o.z = f2h_bits(s[i].z * inv);
        o.w = f2h_bits(s[i].w * inv);
        *(ushort4*)&Pr[k] = o;
    }
}

// ---------- fallback (verified R1 fp32 kernel) ----------
__global__ __launch_bounds__(256, 2) void attn_fp32_flash(
    const float* __restrict__ hidden, const float* __restrict__ keys,
    const float* __restrict__ values, const int* __restrict__ mask,
    float* __restrict__ out)
{
    const int lane = threadIdx.x & 63;
    const int wave = threadIdx.x >> 6;
    const int blk  = blockIdx.x;
    const int b    = blk >> 7;
    const int q0   = (blk & 127) * 16 + wave * 4;
    float4 q[4][4]; float4 o[4][4]; float m[4], s[4];
    const float4* hp = (const float4*)(hidden + ((size_t)b * LQ_ + q0) * D_);
#pragma unroll
    for (int r = 0; r < 4; ++r) {
#pragma unroll
        for (int j = 0; j < 4; ++j) {
            q[r][j] = hp[r * 256 + j * 64 + lane];
            o[r][j] = make_float4(0.f, 0.f, 0.f, 0.f);
        }
        m[r] = -INFINITY; s[r] = 0.f;
    }
    const float4* kp = (const float4*)(keys   + (size_t)b * LK_ * D_);
    const float4* vp = (const float4*)(values + (size_t)b * LK_ * D_);
    const int*    mp = mask + b * LK_;
    for (int k = 0; k < LK_; ++k) {
        float4 kv[4];
#pragma unroll
        for (int j = 0; j < 4; ++j) kv[j] = kp[k * 256 + j * 64 + lane];
        float sc[4];
#pragma unroll
        for (int r = 0; r < 4; ++r) {
            float p = 0.f;
#pragma unroll
            for (int j = 0; j < 4; ++j)
                p += q[r][j].x * kv[j].x + q[r][j].y * kv[j].y +
                     q[r][j].z * kv[j].z + q[r][j].w * kv[j].w;
            sc[r] = p;
        }
#pragma unroll
        for (int r = 0; r < 4; ++r)
#pragma unroll
            for (int off = 32; off > 0; off >>= 1)
                sc[r] += __shfl_xor(sc[r], off, 64);
        const int mk = mp[k];
        float4 vv[4];
#pragma unroll
        for (int j = 0; j < 4; ++j) vv[j] = vp[k * 256 + j * 64 + lane];
#pragma unroll
        for (int r = 0; r < 4; ++r) {
            float score = mk ? sc[r] : NEG_INF;
            if (score > m[r]) {
                float scale = __expf(m[r] - score);
                m[r] = score; s[r] *= scale;
#pragma unroll
                for (int j = 0; j < 4; ++j) {
                    o[r][j].x *= scale; o[r][j].y *= scale;
                    o[r][j].z *= scale; o[r][j].w *= scale;
                }
            }
            float e = __expf(score - m[r]);
            s[r] += e;
#pragma unroll
            for (int j = 0; j < 4; ++j) {
                o[r][j].x += e * vv[j].x; o[r][j].y += e * vv[j].y;
                o[r][j].z += e * vv[j].z; o[r][j].w += e * vv[j].w;
            }
        }
    }
    float4* op = (float4*)(out + ((size_t)b * LQ_ + q0) * D_);
#pragma unroll
    for (int r = 0; r < 4; ++r) {
        float inv = 1.f / s[r];
#pragma unroll
        for (int j = 0; j < 4; ++j) {
            float4 t = o[r][j];
            t.x *= inv; t.y *= inv; t.z *= inv; t.w *= inv;
            op[r * 256 + j * 64 + lane] = t;
        }
    }
}

extern "C" void kernel_launch(void* const* d_in, const int* in_sizes, int n_in,
                              void* d_out, int out_size, void* d_ws, size_t ws_size,
                              hipStream_t stream) {
    const float* hidden = (const float*)d_in[0];
    const float* keys   = (const float*)d_in[1];
    const float* values = (const float*)d_in[2];
    const int*   mask   = (const int*)d_in[3];
    float* out = (float*)d_out;
    char* ws = (char*)d_ws;

    const size_t TEN = (size_t)LK_ * D_;          // 2M elems per batch tensor
    const size_t MB  = 1024ull * 1024;

    // per-batch footprint: Kh 4 + VT 4 + Qh 4 + S 16 (P in place) = 28 MiB
    int BG = 0;
    for (int g = 8; g >= 1; g >>= 1)
        if ((size_t)g * 28 * MB <= ws_size) { BG = g; break; }

    if (BG == 0) {
        attn_fp32_flash<<<1024, 256, 0, stream>>>(hidden, keys, values, mask, out);
        return;
    }

    const size_t SZ_BF = (size_t)BG * TEN * 2;            // BG*4 MiB per u16 tensor
    u16*   Kh = (u16*)(ws);
    u16*   VT = (u16*)(ws + SZ_BF);
    u16*   Qh = (u16*)(ws + 2 * SZ_BF);
    float* S  = (float*)(ws + 3 * SZ_BF);                 // BG*16 MiB

    const int n4 = BG * (int)(TEN / 4);

    for (int bg0 = 0; bg0 < B_; bg0 += BG) {
        const size_t off = (size_t)bg0 * TEN;
        // K and Q fp16 converts fused into one dispatch
        convert_f16_2<<<4096, 256, 0, stream>>>(
            (const float4*)(keys + off), (ushort4*)Kh,
            (const float4*)(hidden + off), (ushort4*)Qh, n4);
        transpose_convert<<<dim3(16, 32, BG), 256, 0, stream>>>(
            values + off, VT);

        // S = Qh * Kh^T — pure fp16, true K=1024 (32 tiles), 8x8 grid
        gemm8p<4, 32, false><<<dim3(64, BG), 512, 0, stream>>>(
            Qh, Qh, Kh, S, D_, D_, LK_, 1023,
            TEN, TEN, (size_t)LQ_ * LK_);

        // softmax, P written fp16 in place over the first half of each S row
        softmax_mask<<<dim3(LQ_ / 4, BG), 256, 0, stream>>>(
            S, mask + bg0 * LK_);

        // out = P * VT^T — 256x256 tile (NBF=4), 8m x 4n grid = 32 blocks/batch;
        // P rows at stride 4096 u16 inside S; virtual K=2048 via A1 = P + 1024
        gemm8p<4, 64, true><<<dim3(32, BG), 512, 0, stream>>>(
            (const u16*)S, (const u16*)S + 1024, VT, out + off,
            2 * LK_, LK_, D_, 2047,
            (size_t)LQ_ * 2 * LK_, TEN, (size_t)LQ_ * D_);
    }
}

// Round 15
// 235.812 us; speedup vs baseline: 1.3612x; 1.0129x over previous
//
#include <hip/hip_runtime.h>

#define NEG_INF -1e10f
#define B_   8
#define LQ_  2048
#define LK_  2048
#define D_   1024

typedef unsigned int uint;
typedef unsigned short u16;
typedef _Float16 f16;
typedef _Float16 f16x8_t __attribute__((ext_vector_type(8)));
typedef float f32x4_t __attribute__((ext_vector_type(4)));

// ---------- helpers ----------
__device__ __forceinline__ u16 f2h_bits(float f) {
    f16 h = (f16)f;
    return __builtin_bit_cast(u16, h);
}
__device__ __forceinline__ void gload_lds16(const void* g, void* l) {
    __builtin_amdgcn_global_load_lds(
        (const __attribute__((address_space(1))) uint*)g,
        (__attribute__((address_space(3))) uint*)l, 16, 0, 0);
}

// ---------- fused fp32 -> fp16 for two tensors (K and Q) ----------
__global__ __launch_bounds__(256) void convert_f16_2(
    const float4* __restrict__ s1, ushort4* __restrict__ d1,
    const float4* __restrict__ s2, ushort4* __restrict__ d2, int n4)
{
    int idx = blockIdx.x * 256 + threadIdx.x;
    const int stride = gridDim.x * 256;
    for (; idx < 2 * n4; idx += stride) {
        const bool second = idx >= n4;
        const int i = second ? idx - n4 : idx;
        float4 x = second ? s2[i] : s1[i];
        ushort4 h;
        h.x = f2h_bits(x.x);
        h.y = f2h_bits(x.y);
        h.z = f2h_bits(x.z);
        h.w = f2h_bits(x.w);
        if (second) d2[i] = h; else d1[i] = h;
    }
}

// ---------- V [z][2048][1024] fp32 -> VT [z][1024][2048] fp16 ----------
__global__ __launch_bounds__(256) void transpose_convert(
    const float* __restrict__ V, u16* __restrict__ VT)
{
    __shared__ float tile[64][65];
    const int t  = threadIdx.x;
    const int d0 = blockIdx.x * 64;
    const int k0 = blockIdx.y * 64;
    const float* Vb = V + (size_t)blockIdx.z * (LK_ * D_);
    u16* VTb = VT + (size_t)blockIdx.z * (D_ * LK_);
#pragma unroll
    for (int i = 0; i < 4; ++i) {
        int f = i * 256 + t;
        int r = f >> 4, c4 = f & 15;
        float4 v = *(const float4*)&Vb[(size_t)(k0 + r) * D_ + d0 + c4 * 4];
        tile[r][c4 * 4 + 0] = v.x;
        tile[r][c4 * 4 + 1] = v.y;
        tile[r][c4 * 4 + 2] = v.z;
        tile[r][c4 * 4 + 3] = v.w;
    }
    __syncthreads();
#pragma unroll
    for (int i = 0; i < 4; ++i) {
        int f = i * 256 + t;
        int d = f >> 4, c4 = f & 15;
        ushort4 o;
        o.x = f2h_bits(tile[c4 * 4 + 0][d]);
        o.y = f2h_bits(tile[c4 * 4 + 1][d]);
        o.z = f2h_bits(tile[c4 * 4 + 2][d]);
        o.w = f2h_bits(tile[c4 * 4 + 3][d]);
        *(ushort4*)&VTb[(size_t)(d0 + d) * LK_ + k0 + c4 * 4] = o;
    }
}

#define DSR(dst, base, off) \
    asm volatile("ds_read_b128 %0, %1 offset:" off : "=v"(dst) : "v"(base))

// ===================================================================
// gemm_qk2: S = Qh * Kh^T, K=1024 (32 tiles of BK=32), pure fp16.
// 256x256 tile, 8 waves (2M x 4N), RING-2 LDS (64 KiB -> 2 blocks/CU).
// Protocol = R10's race-verified single-barrier ring-2 (absmax was
// bit-identical); R10's failure was launch_bounds(512,4) forcing
// VGPR<=128 -> acc spill.  Here (512,2): ~160 VGPR free, no spill;
// co-residency comes from LDS (64 KiB -> 2 blocks/CU), and block A's
// vmcnt(0)+barrier drain hides under block B's MFMA (m114 mechanism).
// Per tile t:  vmcnt(0)   [my stage(t) gloads done]
//              barrier    [all waves' t-writes visible; buf[(t+1)&1]'s
//                          prior readers drained (their lgkmcnt(0) in
//                          tile t-1 preceded this barrier)]
//              stage(t+1) -> buf[(t+1)&1]
//              DSR 12 frags from buf[t&1]
//              lgkmcnt(4) -> B + A-mh0 ready; 16 MFMA mh0
//              lgkmcnt(0) -> A-mh1 ready;     16 MFMA mh1
// ===================================================================
__global__ __launch_bounds__(512, 2) void gemm_qk2(
    const u16* __restrict__ Ag, const u16* __restrict__ Bg,
    float* __restrict__ Cg, size_t szA, size_t szB, size_t szC)
{
    constexpr int NT     = 32;
    constexpr int ABYTES = 256 * 32 * 2;           // 16384
    constexpr int BUFSZ  = 2 * ABYTES;             // 32768 (A + B)
    __shared__ char lds[2 * BUFSZ];                // 64 KiB

    const int tid  = threadIdx.x;
    const int lane = tid & 63;
    const int w    = tid >> 6;
    const int wm   = w >> 2;             // 0..1
    const int wn   = w & 3;              // 0..3

    // T1 XCD 2x4 rectangle remap (8x8 tile grid) — R9-verified
    const int d  = blockIdx.x;
    const int g  = d & 7;
    const int k_ = d >> 3;
    const int m0 = ((g >> 1) * 2 + (k_ & 1)) * 256;
    const int n0 = ((g & 1) * 4 + (k_ >> 1)) * 256;
    const size_t z = blockIdx.y;

    const u16* A = Ag + z * szA;
    const u16* B = Bg + z * szB;
    float* C = Cg + z * szC;

    const uint ldsbase = (uint)(size_t)&lds[0];
    const int  lr   = lane & 15;
    // T2 swizzle (R7-verified, conflicts = 0)
    const uint csel = (uint)((((lane >> 4) ^ ((lane >> 1) & 3)) * 16));
    const int  cstg = (((lane & 3) ^ ((lane >> 3) & 3)) * 8);
    const int  rstg = lane >> 2;

    const uint awoff = (uint)(wm * 8192 + lr * 64) + csel;
    const uint bwoff = (uint)(wn * 4096 + lr * 64) + csel;

    f32x4_t acc[8][4];
#pragma unroll
    for (int m = 0; m < 8; ++m)
#pragma unroll
        for (int n = 0; n < 4; ++n)
            acc[m][n] = (f32x4_t){0.f, 0.f, 0.f, 0.f};

    auto stage = [&](int t) {
        const int kc = t * 32 + cstg;
        char* dA = lds + (t & 1) * BUFSZ + w * 2048;
        char* dB = lds + (t & 1) * BUFSZ + ABYTES + w * 2048;
        gload_lds16(&A[(size_t)(m0 + w * 32 + rstg) * D_ + kc], dA);
        gload_lds16(&A[(size_t)(m0 + w * 32 + 16 + rstg) * D_ + kc], dA + 1024);
        gload_lds16(&B[(size_t)(n0 + w * 32 + rstg) * D_ + kc], dB);
        gload_lds16(&B[(size_t)(n0 + w * 32 + 16 + rstg) * D_ + kc], dB + 1024);
    };

    stage(0);   // prologue

    f16x8_t a0[4], a1[4], b[4];
    for (int t = 0; t < NT; ++t) {
        asm volatile("s_waitcnt vmcnt(0)" ::: "memory");
        __builtin_amdgcn_s_barrier();
        if (t + 1 < NT) stage(t + 1);
        const uint aA = ldsbase + (uint)((t & 1) * BUFSZ) + awoff;
        const uint aB = ldsbase + (uint)((t & 1) * BUFSZ + ABYTES) + bwoff;
        DSR(b[0], aB, "0");     DSR(b[1], aB, "1024");
        DSR(b[2], aB, "2048");  DSR(b[3], aB, "3072");
        DSR(a0[0], aA, "0");    DSR(a0[1], aA, "1024");
        DSR(a0[2], aA, "2048"); DSR(a0[3], aA, "3072");
        DSR(a1[0], aA, "4096"); DSR(a1[1], aA, "5120");
        DSR(a1[2], aA, "6144"); DSR(a1[3], aA, "7168");
        asm volatile("s_waitcnt lgkmcnt(4)");
        __builtin_amdgcn_sched_barrier(0);
        __builtin_amdgcn_s_setprio(1);
#pragma unroll
        for (int mf = 0; mf < 4; ++mf)
#pragma unroll
            for (int nf = 0; nf < 4; ++nf)
                acc[mf][nf] = __builtin_amdgcn_mfma_f32_16x16x32_f16(
                    a0[mf], b[nf], acc[mf][nf], 0, 0, 0);
        asm volatile("s_waitcnt lgkmcnt(0)");
        __builtin_amdgcn_sched_barrier(0);
#pragma unroll
        for (int mf = 0; mf < 4; ++mf)
#pragma unroll
            for (int nf = 0; nf < 4; ++nf)
                acc[4 + mf][nf] = __builtin_amdgcn_mfma_f32_16x16x32_f16(
                    a1[mf], b[nf], acc[4 + mf][nf], 0, 0, 0);
        __builtin_amdgcn_s_setprio(0);
    }

    const int cg = lane >> 4;
#pragma unroll
    for (int mf = 0; mf < 8; ++mf)
#pragma unroll
        for (int nf = 0; nf < 4; ++nf) {
            const int row = m0 + wm * 128 + mf * 16 + cg * 4;
            const int col = n0 + wn * 64 + nf * 16 + lr;
#pragma unroll
            for (int r = 0; r < 4; ++r)
                C[(size_t)(row + r) * LK_ + col] = acc[mf][nf][r];
        }
}

// ===================================================================
// gemm8p (PV): R11-R14-verified 8-phase counted-vmcnt, 256x256 tile,
// ring-4 (128 KiB).  Virtual K=2048 via A-pointer switch (P rows in S).
// ===================================================================
#define BM_  256
#define BK_  32

template<int NTILES>
__global__ __launch_bounds__(512, 2) void gemm8p(
    const u16* __restrict__ A0g, const u16* __restrict__ A1g,
    const u16* __restrict__ Bg, float* __restrict__ Cg,
    int lda, int ldb, int ldc, int bkmask,
    size_t szA, size_t szB, size_t szC)
{
    constexpr int NBF    = 4;
    constexpr int BN     = 64 * NBF;
    constexpr int ABYTES = BM_ * BK_ * 2;          // 16384
    constexpr int BBYTES = BN * BK_ * 2;           // 16384
    constexpr int BUFSZ  = ABYTES + BBYTES;        // 32768
    __shared__ char lds[4 * BUFSZ];

    const int tid  = threadIdx.x;
    const int lane = tid & 63;
    const int w    = tid >> 6;           // 0..7
    const int wm   = w >> 2;             // 0..1
    const int wn   = w & 3;              // 0..3

    // PV: 8m x 4n grid, XCD owns 2m x 2n rect
    const int d  = blockIdx.x;
    const int g  = d & 7;
    const int k_ = d >> 3;
    const int by = (g >> 1) * 2 + (k_ & 1);
    const int bx = (g & 1) * 2 + (k_ >> 1);
    const int m0 = by * BM_;
    const int n0 = bx * BN;
    const size_t z = blockIdx.y;

    const u16* A0 = A0g + z * szA;
    const u16* A1 = A1g + z * szA;
    const u16* B  = Bg  + z * szB;
    float* C = Cg + z * szC;

    const int  lr   = lane & 15;
    const uint csel = (uint)((((lane >> 4) ^ ((lane >> 1) & 3)) * 16));
    const int  cstg = (((lane & 3) ^ ((lane >> 3) & 3)) * 8);
    const int  rstg = lane >> 2;

    const uint awoff = (uint)(wm * 8192 + lr * 64) + csel;
    const uint bwoff = (uint)(wn * (NBF * 1024) + lr * 64) + csel;

    f32x4_t acc[8][NBF];
#pragma unroll
    for (int m = 0; m < 8; ++m)
#pragma unroll
        for (int n = 0; n < NBF; ++n)
            acc[m][n] = (f32x4_t){0.f, 0.f, 0.f, 0.f};

    auto stA = [&](int t) {
        const u16* Ab = (t < NTILES / 2) ? A0 : A1;
        const int kc = (t & (NTILES / 2 - 1)) * BK_ + cstg;
        char* dst = lds + (t & 3) * BUFSZ + w * 2048;
        gload_lds16(&Ab[(size_t)(m0 + w * 32 + rstg) * lda + kc], dst);
        gload_lds16(&Ab[(size_t)(m0 + w * 32 + 16 + rstg) * lda + kc], dst + 1024);
    };
    auto stB = [&](int t) {
        const int kc = ((t * BK_) & bkmask) + cstg;
        char* dst = lds + (t & 3) * BUFSZ + ABYTES;
        gload_lds16(&B[(size_t)(n0 + w * 32 + rstg) * ldb + kc], dst + w * 2048);
        gload_lds16(&B[(size_t)(n0 + w * 32 + 16 + rstg) * ldb + kc], dst + w * 2048 + 1024);
    };

    stA(0); stB(0); stA(1); stB(1); stA(2); stB(2);
    asm volatile("s_waitcnt vmcnt(8)" ::: "memory");
    __builtin_amdgcn_s_barrier();

#define LDF(p) (*(const f16x8_t*)(p))

#define PHASE_A(T, DOSTAGE)                                                   \
    {                                                                         \
        const char* pA = lds + ((T) & 3) * BUFSZ + awoff;                     \
        const char* pB = lds + ((T) & 3) * BUFSZ + ABYTES + bwoff;            \
        f16x8_t a[4], b[NBF];                                                 \
        a[0] = LDF(pA);        a[1] = LDF(pA + 1024);                         \
        a[2] = LDF(pA + 2048); a[3] = LDF(pA + 3072);                         \
        b[0] = LDF(pB);        b[1] = LDF(pB + 1024);                         \
        b[2] = LDF(pB + 2048); b[3] = LDF(pB + 3072);                         \
        if (DOSTAGE) stA((T) + 3);                                            \
        __builtin_amdgcn_s_barrier();                                         \
        __builtin_amdgcn_s_setprio(1);                                        \
        _Pragma("unroll")                                                     \
        for (int mf = 0; mf < 4; ++mf)                                        \
            _Pragma("unroll")                                                 \
            for (int nf = 0; nf < NBF; ++nf)                                  \
                acc[mf][nf] = __builtin_amdgcn_mfma_f32_16x16x32_f16(         \
                    a[mf], b[nf], acc[mf][nf], 0, 0, 0);                      \
        __builtin_amdgcn_s_setprio(0);                                        \
        bsave[0] = b[0]; bsave[1] = b[1]; bsave[2] = b[2]; bsave[3] = b[3];   \
        __builtin_amdgcn_s_barrier();                                         \
    }

#define PHASE_B(T, DOSTAGE, VMASM)                                            \
    {                                                                         \
        const char* pA = lds + ((T) & 3) * BUFSZ + awoff;                     \
        f16x8_t a[4];                                                         \
        a[0] = LDF(pA + 4096); a[1] = LDF(pA + 5120);                         \
        a[2] = LDF(pA + 6144); a[3] = LDF(pA + 7168);                         \
        if (DOSTAGE) stB((T) + 3);                                            \
        __builtin_amdgcn_s_barrier();                                         \
        __builtin_amdgcn_s_setprio(1);                                        \
        _Pragma("unroll")                                                     \
        for (int mf = 0; mf < 4; ++mf)                                        \
            _Pragma("unroll")                                                 \
            for (int nf = 0; nf < NBF; ++nf)                                  \
                acc[4 + mf][nf] = __builtin_amdgcn_mfma_f32_16x16x32_f16(     \
                    a[mf], bsave[nf], acc[4 + mf][nf], 0, 0, 0);              \
        __builtin_amdgcn_s_setprio(0);                                        \
        VMASM;                                                                \
        __builtin_amdgcn_s_barrier();                                         \
    }

#define VMW asm volatile("s_waitcnt vmcnt(8)" ::: "memory")
#define VMH asm volatile("s_waitcnt vmcnt(4)" ::: "memory")
#define VM0 asm volatile("s_waitcnt vmcnt(0)" ::: "memory")
#define VMN do {} while (0)

    f16x8_t bsave[NBF];

    for (int t = 0; t < NTILES - 3; ++t) {
        PHASE_A(t, true);
        PHASE_B(t, true, VMW);
    }
    PHASE_A(NTILES - 3, false); PHASE_B(NTILES - 3, false, VMH);
    PHASE_A(NTILES - 2, false); PHASE_B(NTILES - 2, false, VM0);
    PHASE_A(NTILES - 1, false); PHASE_B(NTILES - 1, false, VMN);
#undef PHASE_A
#undef PHASE_B
#undef LDF

    const int cg = lane >> 4;
#pragma unroll
    for (int mf = 0; mf < 8; ++mf)
#pragma unroll
        for (int nf = 0; nf < NBF; ++nf) {
            const int row = m0 + wm * 128 + mf * 16 + cg * 4;
            const int col = n0 + wn * (NBF * 16) + nf * 16 + lr;
#pragma unroll
            for (int r = 0; r < 4; ++r)
                C[(size_t)(row + r) * ldc + col] = acc[mf][nf][r];
        }
}

// ---------- masked row softmax, z-batched: S fp32 -> P fp16 IN PLACE ----------
__global__ __launch_bounds__(256) void softmax_mask(
    float* __restrict__ S, const int* __restrict__ mask0)
{
    const int lane = threadIdx.x & 63;
    const int wave = threadIdx.x >> 6;
    const int row  = blockIdx.x * 4 + wave;
    const size_t zb = blockIdx.y;
    float* Sr = S + (zb * LQ_ + row) * (size_t)LK_;
    const int* mb = mask0 + zb * LK_;

    float4 s[8];
    float m = -INFINITY;
#pragma unroll
    for (int i = 0; i < 8; ++i) {
        int k = i * 256 + lane * 4;
        float4 v = *(const float4*)&Sr[k];
        int4 mk  = *(const int4*)&mb[k];
        v.x = mk.x ? v.x : NEG_INF;
        v.y = mk.y ? v.y : NEG_INF;
        v.z = mk.z ? v.z : NEG_INF;
        v.w = mk.w ? v.w : NEG_INF;
        s[i] = v;
        m = fmaxf(m, fmaxf(fmaxf(v.x, v.y), fmaxf(v.z, v.w)));
    }
#pragma unroll
    for (int off = 32; off > 0; off >>= 1)
        m = fmaxf(m, __shfl_xor(m, off, 64));
    float sum = 0.f;
#pragma unroll
    for (int i = 0; i < 8; ++i) {
        s[i].x = __expf(s[i].x - m); sum += s[i].x;
        s[i].y = __expf(s[i].y - m); sum += s[i].y;
        s[i].z = __expf(s[i].z - m); sum += s[i].z;
        s[i].w = __expf(s[i].w - m); sum += s[i].w;
    }
#pragma unroll
    for (int off = 32; off > 0; off >>= 1)
        sum += __shfl_xor(sum, off, 64);
    const float inv = 1.f / sum;
    u16* Pr = (u16*)Sr;
#pragma unroll
    for (int i = 0; i < 8; ++i) {
        int k = i * 256 + lane * 4;
        ushort4 o;
        o.x = f2h_bits(s[i].x * inv);
        o.y = f2h_bits(s[i].y * inv);
        o.z = f2h_bits(s[i].z * inv);
        o.w = f2h_bits(s[i].w * inv);
        *(ushort4*)&Pr[k] = o;
    }
}

// ---------- fallback (verified R1 fp32 kernel) ----------
__global__ __launch_bounds__(256, 2) void attn_fp32_flash(
    const float* __restrict__ hidden, const float* __restrict__ keys,
    const float* __restrict__ values, const int* __restrict__ mask,
    float* __restrict__ out)
{
    const int lane = threadIdx.x & 63;
    const int wave = threadIdx.x >> 6;
    const int blk  = blockIdx.x;
    const int b    = blk >> 7;
    const int q0   = (blk & 127) * 16 + wave * 4;
    float4 q[4][4]; float4 o[4][4]; float m[4], s[4];
    const float4* hp = (const float4*)(hidden + ((size_t)b * LQ_ + q0) * D_);
#pragma unroll
    for (int r = 0; r < 4; ++r) {
#pragma unroll
        for (int j = 0; j < 4; ++j) {
            q[r][j] = hp[r * 256 + j * 64 + lane];
            o[r][j] = make_float4(0.f, 0.f, 0.f, 0.f);
        }
        m[r] = -INFINITY; s[r] = 0.f;
    }
    const float4* kp = (const float4*)(keys   + (size_t)b * LK_ * D_);
    const float4* vp = (const float4*)(values + (size_t)b * LK_ * D_);
    const int*    mp = mask + b * LK_;
    for (int k = 0; k < LK_; ++k) {
        float4 kv[4];
#pragma unroll
        for (int j = 0; j < 4; ++j) kv[j] = kp[k * 256 + j * 64 + lane];
        float sc[4];
#pragma unroll
        for (int r = 0; r < 4; ++r) {
            float p = 0.f;
#pragma unroll
            for (int j = 0; j < 4; ++j)
                p += q[r][j].x * kv[j].x + q[r][j].y * kv[j].y +
                     q[r][j].z * kv[j].z + q[r][j].w * kv[j].w;
            sc[r] = p;
        }
#pragma unroll
        for (int r = 0; r < 4; ++r)
#pragma unroll
            for (int off = 32; off > 0; off >>= 1)
                sc[r] += __shfl_xor(sc[r], off, 64);
        const int mk = mp[k];
        float4 vv[4];
#pragma unroll
        for (int j = 0; j < 4; ++j) vv[j] = vp[k * 256 + j * 64 + lane];
#pragma unroll
        for (int r = 0; r < 4; ++r) {
            float score = mk ? sc[r] : NEG_INF;
            if (score > m[r]) {
                float scale = __expf(m[r] - score);
                m[r] = score; s[r] *= scale;
#pragma unroll
                for (int j = 0; j < 4; ++j) {
                    o[r][j].x *= scale; o[r][j].y *= scale;
                    o[r][j].z *= scale; o[r][j].w *= scale;
                }
            }
            float e = __expf(score - m[r]);
            s[r] += e;
#pragma unroll
            for (int j = 0; j < 4; ++j) {
                o[r][j].x += e * vv[j].x; o[r][j].y += e * vv[j].y;
                o[r][j].z += e * vv[j].z; o[r][j].w += e * vv[j].w;
            }
        }
    }
    float4* op = (float4*)(out + ((size_t)b * LQ_ + q0) * D_);
#pragma unroll
    for (int r = 0; r < 4; ++r) {
        float inv = 1.f / s[r];
#pragma unroll
        for (int j = 0; j < 4; ++j) {
            float4 t = o[r][j];
            t.x *= inv; t.y *= inv; t.z *= inv; t.w *= inv;
            op[r * 256 + j * 64 + lane] = t;
        }
    }
}

extern "C" void kernel_launch(void* const* d_in, const int* in_sizes, int n_in,
                              void* d_out, int out_size, void* d_ws, size_t ws_size,
                              hipStream_t stream) {
    const float* hidden = (const float*)d_in[0];
    const float* keys   = (const float*)d_in[1];
    const float* values = (const float*)d_in[2];
    const int*   mask   = (const int*)d_in[3];
    float* out = (float*)d_out;
    char* ws = (char*)d_ws;

    const size_t TEN = (size_t)LK_ * D_;          // 2M elems per batch tensor
    const size_t MB  = 1024ull * 1024;

    // per-batch footprint: Kh 4 + VT 4 + Qh 4 + S 16 (P in place) = 28 MiB
    int BG = 0;
    for (int g = 8; g >= 1; g >>= 1)
        if ((size_t)g * 28 * MB <= ws_size) { BG = g; break; }

    if (BG == 0) {
        attn_fp32_flash<<<1024, 256, 0, stream>>>(hidden, keys, values, mask, out);
        return;
    }

    const size_t SZ_BF = (size_t)BG * TEN * 2;            // BG*4 MiB per u16 tensor
    u16*   Kh = (u16*)(ws);
    u16*   VT = (u16*)(ws + SZ_BF);
    u16*   Qh = (u16*)(ws + 2 * SZ_BF);
    float* S  = (float*)(ws + 3 * SZ_BF);                 // BG*16 MiB

    const int n4 = BG * (int)(TEN / 4);

    for (int bg0 = 0; bg0 < B_; bg0 += BG) {
        const size_t off = (size_t)bg0 * TEN;
        // K and Q fp16 converts fused into one dispatch
        convert_f16_2<<<4096, 256, 0, stream>>>(
            (const float4*)(keys + off), (ushort4*)Kh,
            (const float4*)(hidden + off), (ushort4*)Qh, n4);
        transpose_convert<<<dim3(16, 32, BG), 256, 0, stream>>>(
            values + off, VT);

        // S = Qh * Kh^T — ring-2 (64 KiB), 2 blocks/CU co-resident
        gemm_qk2<<<dim3(64, BG), 512, 0, stream>>>(
            Qh, Kh, S, TEN, TEN, (size_t)LQ_ * LK_);

        // softmax, P written fp16 in place over the first half of each S row
        softmax_mask<<<dim3(LQ_ / 4, BG), 256, 0, stream>>>(
            S, mask + bg0 * LK_);

        // out = P * VT^T — 256x256 tile, ring-4; P rows at stride 4096 u16
        gemm8p<64><<<dim3(32, BG), 512, 0, stream>>>(
            (const u16*)S, (const u16*)S + 1024, VT, out + off,
            2 * LK_, LK_, D_, 2047,
            (size_t)LQ_ * 2 * LK_, TEN, (size_t)LQ_ * D_);
    }
}